// Round 18
// baseline (307.376 us; speedup 1.0000x reference)
//
#include <hip/hip_runtime.h>
#include <hip/hip_fp16.h>

#define N_NODES 100000
#define N_EDGES 1600000
#define E_TOT   (N_EDGES + N_NODES)
#define NEG_SLOPE 0.2f

#define BSH   9
#define BSZ   512                         // nodes per bucket
#define NBKT  ((N_NODES + BSZ - 1) / BSZ) // 196
#define CAP   10240                       // padded bucket capacity (mean 8673)
#define EPB   4096                        // edges per partition block
#define PART_B ((E_TOT + EPB - 1) / EPB)  // 416
#define GEMM1_B ((N_NODES + 63) / 64)     // 1563

__device__ __forceinline__ float lrelu(float v) { return v > 0.f ? v : NEG_SLOPE * v; }

__device__ __forceinline__ float f16lo(unsigned u) {
    return __half2float(__ushort_as_half((unsigned short)(u & 0xFFFFu)));
}
__device__ __forceinline__ float f16hi(unsigned u) {
    return __half2float(__ushort_as_half((unsigned short)(u >> 16)));
}
__device__ __forceinline__ unsigned packh2(float a, float b) {
    unsigned lo = __half_as_ushort(__float2half(a));
    unsigned hi = __half_as_ushort(__float2half(b));
    return (hi << 16) | lo;
}

// ---- Fused launch 1: edge partition (blocks [0,PART_B)) + layer-1 GEMM ----
// K-split staging: xs = [64 nodes][64 k] fp32 = 16 KB -> 8 blocks/CU
// (wave-limited), capacity 2048 >= 1979 blocks -> single scheduling round.
// x is read twice (HBM is at 11%, extra ~8 us hidden); acc carried across halves.
__global__ __launch_bounds__(256) void k_part_gemm1(
        const int* __restrict__ ei, int* __restrict__ gcur, int* __restrict__ packed,
        const float* __restrict__ x, const float* __restrict__ W1,
        const float* __restrict__ a_src, const float* __restrict__ a_dst,
        unsigned short* __restrict__ h1h, float* __restrict__ als,
        float* __restrict__ ald) {
    __shared__ __align__(16) union {
        float xs[64 * 64];                        // 16 KB (gemm1 role, one K-half)
        struct { int lcnt[NBKT]; int gpos[NBKT]; int lcur[NBKT]; } p;  // part role
    } sm;
    int t = threadIdx.x;
    if (blockIdx.x < PART_B) {
        // ---------------- partition role ----------------
        for (int i = t; i < NBKT; i += 256) sm.p.lcnt[i] = 0;
        __syncthreads();
        size_t base = (size_t)blockIdx.x * EPB;
        for (int i = t; i < EPB; i += 256) {
            size_t e = base + i;
            if (e < E_TOT) {
                int d = (e < N_EDGES) ? ei[N_EDGES + e] : (int)(e - N_EDGES);
                atomicAdd(&sm.p.lcnt[d >> BSH], 1);
            }
        }
        __syncthreads();
        for (int i = t; i < NBKT; i += 256) {
            int c = sm.p.lcnt[i];
            sm.p.gpos[i] = c ? (i * CAP + atomicAdd(&gcur[i], c)) : 0;
            sm.p.lcur[i] = 0;
        }
        __syncthreads();
        for (int i = t; i < EPB; i += 256) {
            size_t e = base + i;
            if (e < E_TOT) {
                int s, d;
                if (e < N_EDGES) { s = ei[e]; d = ei[N_EDGES + e]; }
                else             { s = (int)(e - N_EDGES); d = s; }
                int b = d >> BSH;
                int c = atomicAdd(&sm.p.lcur[b], 1);
                packed[sm.p.gpos[b] + c] = ((d & (BSZ - 1)) << 17) | s;
            }
        }
        return;
    }
    // ---------------- gemm1 role (one 64-node tile, K split in 2 halves) ----
    int c = t & 31, rg = t >> 5;
    int nb = (blockIdx.x - PART_B) * 64;
    const float4* xv4 = (const float4*)x;
    const float4* W1v = (const float4*)W1;
    float4* xs4 = (float4*)sm.xs;
    float4 acc[8];
#pragma unroll
    for (int i = 0; i < 8; ++i) acc[i] = make_float4(0.f, 0.f, 0.f, 0.f);
#pragma unroll
    for (int h = 0; h < 2; ++h) {
        if (h) __syncthreads();   // WAR: previous half's reads must finish
        // stage half: 64 nodes x 16 float4 (= 1024 float4, 4 per thread)
#pragma unroll
        for (int i = 0; i < 4; ++i) {
            int idx = t + i * 256;               // 0..1023
            int node = idx >> 4, k4i = idx & 15;
            int n = nb + node;
            if (n < N_NODES)
                xs4[idx] = xv4[(size_t)n * 32 + h * 16 + k4i];
        }
        __syncthreads();
        for (int k4 = 0; k4 < 16; ++k4) {
            float4 w0 = W1v[(h * 64 + k4 * 4 + 0) * 32 + c];
            float4 w1 = W1v[(h * 64 + k4 * 4 + 1) * 32 + c];
            float4 w2 = W1v[(h * 64 + k4 * 4 + 2) * 32 + c];
            float4 w3 = W1v[(h * 64 + k4 * 4 + 3) * 32 + c];
#pragma unroll
            for (int i = 0; i < 8; ++i) {
                float4 xq = *(const float4*)&sm.xs[(rg + 8 * i) * 64 + k4 * 4];
                acc[i].x = fmaf(xq.x, w0.x, acc[i].x);
                acc[i].y = fmaf(xq.x, w0.y, acc[i].y);
                acc[i].z = fmaf(xq.x, w0.z, acc[i].z);
                acc[i].w = fmaf(xq.x, w0.w, acc[i].w);
                acc[i].x = fmaf(xq.y, w1.x, acc[i].x);
                acc[i].y = fmaf(xq.y, w1.y, acc[i].y);
                acc[i].z = fmaf(xq.y, w1.z, acc[i].z);
                acc[i].w = fmaf(xq.y, w1.w, acc[i].w);
                acc[i].x = fmaf(xq.z, w2.x, acc[i].x);
                acc[i].y = fmaf(xq.z, w2.y, acc[i].y);
                acc[i].z = fmaf(xq.z, w2.z, acc[i].z);
                acc[i].w = fmaf(xq.z, w2.w, acc[i].w);
                acc[i].x = fmaf(xq.w, w3.x, acc[i].x);
                acc[i].y = fmaf(xq.w, w3.y, acc[i].y);
                acc[i].z = fmaf(xq.w, w3.z, acc[i].z);
                acc[i].w = fmaf(xq.w, w3.w, acc[i].w);
            }
        }
    }
    float4 as4 = ((const float4*)a_src)[c];
    float4 ad4 = ((const float4*)a_dst)[c];
#pragma unroll
    for (int i = 0; i < 8; ++i) {
        int n = nb + rg + 8 * i;
        if (n < N_NODES) {
            ushort4 hb;
            hb.x = __half_as_ushort(__float2half(acc[i].x));
            hb.y = __half_as_ushort(__float2half(acc[i].y));
            hb.z = __half_as_ushort(__float2half(acc[i].z));
            hb.w = __half_as_ushort(__float2half(acc[i].w));
            ((ushort4*)h1h)[(size_t)n * 32 + c] = hb;
        }
        float vs = acc[i].x * as4.x + acc[i].y * as4.y + acc[i].z * as4.z + acc[i].w * as4.w;
        float vd = acc[i].x * ad4.x + acc[i].y * ad4.y + acc[i].z * ad4.z + acc[i].w * ad4.w;
        vs += __shfl_down(vs, 4, 8); vs += __shfl_down(vs, 2, 8); vs += __shfl_down(vs, 1, 8);
        vd += __shfl_down(vd, 4, 8); vd += __shfl_down(vd, 2, 8); vd += __shfl_down(vd, 1, 8);
        if ((c & 7) == 0 && n < N_NODES) {
            int h2 = c >> 3;
            als[n * 4 + h2] = vs;
            ald[n * 4 + h2] = vd;
        }
    }
}

// ---- per-bucket: count from cursor, local scan -> rowptr+deg, col scatter ----
__global__ __launch_bounds__(512) void k_build(const int* __restrict__ packed,
                                               const int* __restrict__ gcur,
                                               int* __restrict__ rowptr,
                                               int* __restrict__ deg,
                                               int* __restrict__ col) {
    int t = threadIdx.x;
    int b = blockIdx.x;
    int nb = b << BSH;
    int ebeg = b * CAP;
    int eend = ebeg + gcur[b];     // relative cursor
    __shared__ int cnt[BSZ];
    __shared__ int ps[BSZ];
    cnt[t] = 0;
    __syncthreads();
    for (int i = ebeg + t; i < eend; i += 512)
        atomicAdd(&cnt[packed[i] >> 17], 1);
    __syncthreads();
    int v = cnt[t];
    ps[t] = v;
    __syncthreads();
    for (int off = 1; off < 512; off <<= 1) {
        int u = (t >= off) ? ps[t - off] : 0;
        __syncthreads();
        ps[t] += u;
        __syncthreads();
    }
    int myofs = ebeg + ps[t] - v;   // padded-global col offset of node nb+t
    int n = nb + t;
    if (n < N_NODES) { rowptr[n] = myofs; deg[n] = v; }
    __syncthreads();
    cnt[t] = myofs;                  // reuse as global-position cursor
    __syncthreads();
    for (int i = ebeg + t; i < eend; i += 512) {
        int p = packed[i];
        int pos = atomicAdd(&cnt[p >> 17], 1);
        col[pos] = p & 0x1FFFF;
    }
}

// ---- Layer 1 aggregation: wave/node, 4 edges/iter uint4, fp16 out1 ----
__global__ __launch_bounds__(256) void k_agg1(const unsigned short* __restrict__ h1h,
                                              const float* __restrict__ als,
                                              const float* __restrict__ ald,
                                              const int* __restrict__ rowptr,
                                              const int* __restrict__ deg,
                                              const int* __restrict__ col,
                                              const float* __restrict__ b1,
                                              unsigned short* __restrict__ out1h) {
    __shared__ float sex_all[4][64 * 4];   // per-wave ex[q][head]
    __shared__ int   scol_all[4][64];      // per-wave col cache
    int w = threadIdx.x >> 6;
    int lane = threadIdx.x & 63;
    int n = blockIdx.x * 4 + w;
    int slot = lane >> 4, cg = lane & 15;
    int hd = cg >> 2;
    float* sex = sex_all[w];
    int* scol = scol_all[w];
    float4 ald4 = ((const float4*)ald)[n];
    int beg = rowptr[n], dtot = deg[n];
    float a0 = 0.f, a1 = 0.f, a2 = 0.f, a3 = 0.f;
    float a4 = 0.f, a5 = 0.f, a6 = 0.f, a7 = 0.f, den = 0.f;
    const float4* als4p = (const float4*)als;
    for (int base = 0; base < dtot; base += 64) {
        int cnt = min(64, dtot - base);
        int myc = 0;
        if (lane < cnt) myc = col[beg + base + lane];
        // WAR: previous chunk's ds_reads must drain before overwriting LDS
        __asm__ volatile("s_waitcnt lgkmcnt(0)" ::: "memory");
        if (lane < cnt) {
            scol[lane] = myc;
            float4 as4 = als4p[myc];
            float4 e4;
            e4.x = __expf(lrelu(as4.x + ald4.x));
            e4.y = __expf(lrelu(as4.y + ald4.y));
            e4.z = __expf(lrelu(as4.z + ald4.z));
            e4.w = __expf(lrelu(as4.w + ald4.w));
            ((float4*)sex)[lane] = e4;
        }
        __asm__ volatile("s_waitcnt lgkmcnt(0)" ::: "memory");
#pragma unroll 2
        for (int q4 = 0; q4 < cnt; q4 += 4) {
            int myq = q4 + slot;
            int cq = min(myq, cnt - 1);
            int s = scol[cq];
            float ex = (myq < cnt) ? sex[cq * 4 + hd] : 0.f;
            uint4 hv = *(const uint4*)((const char*)h1h + (((size_t)s << 8) + (cg << 4)));
            a0 = fmaf(ex, f16lo(hv.x), a0);
            a1 = fmaf(ex, f16hi(hv.x), a1);
            a2 = fmaf(ex, f16lo(hv.y), a2);
            a3 = fmaf(ex, f16hi(hv.y), a3);
            a4 = fmaf(ex, f16lo(hv.z), a4);
            a5 = fmaf(ex, f16hi(hv.z), a5);
            a6 = fmaf(ex, f16lo(hv.w), a6);
            a7 = fmaf(ex, f16hi(hv.w), a7);
            den += ex;
        }
    }
    a0 += __shfl_xor(a0, 16, 64); a1 += __shfl_xor(a1, 16, 64);
    a2 += __shfl_xor(a2, 16, 64); a3 += __shfl_xor(a3, 16, 64);
    a4 += __shfl_xor(a4, 16, 64); a5 += __shfl_xor(a5, 16, 64);
    a6 += __shfl_xor(a6, 16, 64); a7 += __shfl_xor(a7, 16, 64);
    den += __shfl_xor(den, 16, 64);
    a0 += __shfl_xor(a0, 32, 64); a1 += __shfl_xor(a1, 32, 64);
    a2 += __shfl_xor(a2, 32, 64); a3 += __shfl_xor(a3, 32, 64);
    a4 += __shfl_xor(a4, 32, 64); a5 += __shfl_xor(a5, 32, 64);
    a6 += __shfl_xor(a6, 32, 64); a7 += __shfl_xor(a7, 32, 64);
    den += __shfl_xor(den, 32, 64);
    if (lane < 16) {
        float inv = 1.0f / den;
        float4 bA = ((const float4*)b1)[2 * lane];
        float4 bB = ((const float4*)b1)[2 * lane + 1];
        float o0 = fmaxf(fmaf(a0, inv, bA.x), 0.f);
        float o1 = fmaxf(fmaf(a1, inv, bA.y), 0.f);
        float o2 = fmaxf(fmaf(a2, inv, bA.z), 0.f);
        float o3 = fmaxf(fmaf(a3, inv, bA.w), 0.f);
        float o4 = fmaxf(fmaf(a4, inv, bB.x), 0.f);
        float o5 = fmaxf(fmaf(a5, inv, bB.y), 0.f);
        float o6 = fmaxf(fmaf(a6, inv, bB.z), 0.f);
        float o7 = fmaxf(fmaf(a7, inv, bB.w), 0.f);
        uint4 pk;
        pk.x = packh2(o0, o1);
        pk.y = packh2(o2, o3);
        pk.z = packh2(o4, o5);
        pk.w = packh2(o6, o7);
        ((uint4*)out1h)[(size_t)n * 16 + lane] = pk;  // ch 8*lane..8*lane+7
    }
}

// ---- Layer 2 GEMM: h2(fp16) = out1h(fp16) @ W2, fused logits ----
__global__ __launch_bounds__(256) void k_gemm2(const unsigned short* __restrict__ out1h,
                                               const float* __restrict__ W2,
                                               const float* __restrict__ a_src,
                                               const float* __restrict__ a_dst,
                                               unsigned short* __restrict__ h2h,
                                               float* __restrict__ als,
                                               float* __restrict__ ald) {
    __shared__ __align__(16) float xs[16 * 132];    // 8448 B
    __shared__ __align__(16) float w2t[16 * 132];   // 8448 B, W2T[c][k]
    int t = threadIdx.x;
    // stage W2 transposed: W2 row-major [128][16]
#pragma unroll
    for (int i = 0; i < 8; ++i) {
        int idx = t + i * 256;            // 0..2047
        int k = idx >> 4, c = idx & 15;
        w2t[c * 132 + k] = W2[idx];
    }
    // stage x tile: 16 nodes x 128 ch fp16 = 4 KB = 256 uint4
    {
        uint4 v = ((const uint4*)out1h)[(size_t)blockIdx.x * 256 + t];
        int node = t >> 4, cb = (t & 15) * 8;
        float* dst = &xs[node * 132 + cb];
        dst[0] = f16lo(v.x); dst[1] = f16hi(v.x);
        dst[2] = f16lo(v.y); dst[3] = f16hi(v.y);
        dst[4] = f16lo(v.z); dst[5] = f16hi(v.z);
        dst[6] = f16lo(v.w); dst[7] = f16hi(v.w);
    }
    __syncthreads();
    int r = t >> 4, c = t & 15;
    const float4* xr4 = (const float4*)&xs[r * 132];
    const float4* wr4 = (const float4*)&w2t[c * 132];
    float acc = 0.f;
#pragma unroll 8
    for (int k4 = 0; k4 < 32; ++k4) {
        float4 xv = xr4[k4];
        float4 wv = wr4[k4];
        acc = fmaf(xv.x, wv.x, acc);
        acc = fmaf(xv.y, wv.y, acc);
        acc = fmaf(xv.z, wv.z, acc);
        acc = fmaf(xv.w, wv.w, acc);
    }
    int n = blockIdx.x * 16 + r;
    h2h[(size_t)n * 16 + c] = __half_as_ushort(__float2half(acc));
    float vs = acc * a_src[c];
    float vd = acc * a_dst[c];
#pragma unroll
    for (int off = 8; off >= 1; off >>= 1) {
        vs += __shfl_down(vs, off, 16);
        vd += __shfl_down(vd, off, 16);
    }
    if (c == 0) { als[n] = vs; ald[n] = vd; }
}

// ---- Layer 2 aggregation: wave/node, 16 edges/iter, batched exp in LDS ----
__global__ __launch_bounds__(256) void k_agg2(const unsigned short* __restrict__ h2h,
                                              const float* __restrict__ als,
                                              const float* __restrict__ ald,
                                              const int* __restrict__ rowptr,
                                              const int* __restrict__ deg,
                                              const int* __restrict__ col,
                                              const float* __restrict__ b2,
                                              float* __restrict__ out) {
    __shared__ float sex_all[4][64];
    __shared__ int   scol_all[4][64];
    int w = threadIdx.x >> 6;
    int lane = threadIdx.x & 63;
    int n = blockIdx.x * 4 + w;
    int slot = lane >> 2, q = lane & 3;
    float* sex = sex_all[w];
    int* scol = scol_all[w];
    float ad = ald[n];
    int beg = rowptr[n], dtot = deg[n];
    float a0 = 0.f, a1 = 0.f, a2 = 0.f, a3 = 0.f, den = 0.f;
    for (int base = 0; base < dtot; base += 64) {
        int cnt = min(64, dtot - base);
        int myc = 0;
        if (lane < cnt) myc = col[beg + base + lane];
        __asm__ volatile("s_waitcnt lgkmcnt(0)" ::: "memory");
        if (lane < cnt) {
            scol[lane] = myc;
            sex[lane] = __expf(lrelu(als[myc] + ad));
        }
        __asm__ volatile("s_waitcnt lgkmcnt(0)" ::: "memory");
#pragma unroll 2
        for (int q16 = 0; q16 < cnt; q16 += 16) {
            int myq = q16 + slot;
            int cq = min(myq, cnt - 1);
            int s = scol[cq];
            float ex = (myq < cnt) ? sex[cq] : 0.f;
            uint2 hv = *(const uint2*)((const char*)h2h + ((size_t)s * 32u + (q << 3)));
            a0 = fmaf(ex, f16lo(hv.x), a0);
            a1 = fmaf(ex, f16hi(hv.x), a1);
            a2 = fmaf(ex, f16lo(hv.y), a2);
            a3 = fmaf(ex, f16hi(hv.y), a3);
            den += ex;
        }
    }
#pragma unroll
    for (int off = 4; off <= 32; off <<= 1) {
        a0 += __shfl_xor(a0, off, 64);
        a1 += __shfl_xor(a1, off, 64);
        a2 += __shfl_xor(a2, off, 64);
        a3 += __shfl_xor(a3, off, 64);
        den += __shfl_xor(den, off, 64);
    }
    if (slot == 0) {
        float inv = 1.0f / den;
        float4 b4 = ((const float4*)b2)[q];
        float4 o;
        o.x = fmaf(a0, inv, b4.x);
        o.y = fmaf(a1, inv, b4.y);
        o.z = fmaf(a2, inv, b4.z);
        o.w = fmaf(a3, inv, b4.w);
        ((float4*)out)[(size_t)n * 4 + q] = o;
    }
}

extern "C" void kernel_launch(void* const* d_in, const int* in_sizes, int n_in,
                              void* d_out, int out_size, void* d_ws, size_t ws_size,
                              hipStream_t stream) {
    const float* x   = (const float*)d_in[0];
    const int*   ei  = (const int*)d_in[1];
    const float* W1  = (const float*)d_in[2];
    const float* as1 = (const float*)d_in[3];
    const float* ad1 = (const float*)d_in[4];
    const float* b1  = (const float*)d_in[5];
    const float* W2  = (const float*)d_in[6];
    const float* as2 = (const float*)d_in[7];
    const float* ad2 = (const float*)d_in[8];
    const float* b2  = (const float*)d_in[9];
    float* out = (float*)d_out;

    char* ws = (char*)d_ws;
    size_t off = 0;
    auto alloc = [&](size_t bytes) -> void* {
        void* p = ws + off;
        off += (bytes + 255) & ~(size_t)255;
        return p;
    };
    unsigned short* h1h  = (unsigned short*)alloc((size_t)N_NODES * 128 * 2);
    unsigned short* o1h  = (unsigned short*)alloc((size_t)N_NODES * 128 * 2);
    float* als1v = (float*)alloc((size_t)N_NODES * 4 * 4);
    float* ald1v = (float*)alloc((size_t)N_NODES * 4 * 4);
    unsigned short* h2h = (unsigned short*)alloc((size_t)N_NODES * 16 * 2);
    float* als2v = (float*)alloc((size_t)N_NODES * 4);
    float* ald2v = (float*)alloc((size_t)N_NODES * 4);
    int* rowptr  = (int*)alloc((size_t)N_NODES * 4);
    int* degv    = (int*)alloc((size_t)N_NODES * 4);
    int* gcur    = (int*)alloc((size_t)NBKT * 4);
    int* packed  = (int*)alloc((size_t)NBKT * CAP * 4);
    int* colA    = (int*)alloc((size_t)NBKT * CAP * 4);

    hipMemsetAsync(gcur, 0, (size_t)NBKT * 4, stream);
    k_part_gemm1<<<PART_B + GEMM1_B, 256, 0, stream>>>(ei, gcur, packed,
                                                       x, W1, as1, ad1, h1h, als1v, ald1v);
    k_build<<<NBKT, 512, 0, stream>>>(packed, gcur, rowptr, degv, colA);
    k_agg1<<<N_NODES / 4, 256, 0, stream>>>(h1h, als1v, ald1v, rowptr, degv, colA, b1, o1h);
    k_gemm2<<<N_NODES / 16, 256, 0, stream>>>(o1h, W2, as2, ad2, h2h, als2v, ald2v);
    k_agg2<<<N_NODES / 4, 256, 0, stream>>>(h2h, als2v, ald2v, rowptr, degv, colA, b2, out);
}

// Round 21
// 297.147 us; speedup vs baseline: 1.0344x; 1.0344x over previous
//
#include <hip/hip_runtime.h>
#include <hip/hip_fp16.h>

#define N_NODES 100000
#define N_EDGES 1600000
#define E_TOT   (N_EDGES + N_NODES)
#define NEG_SLOPE 0.2f

#define BSH   9
#define BSZ   512                         // nodes per bucket
#define NBKT  ((N_NODES + BSZ - 1) / BSZ) // 196
#define CAP   10240                       // padded bucket capacity (mean 8673)
#define EPB   4096                        // edges per partition block
#define PART_B ((E_TOT + EPB - 1) / EPB)  // 416
#define GEMM1_B ((N_NODES + 63) / 64)     // 1563

typedef _Float16 half2_t __attribute__((ext_vector_type(2)));

__device__ __forceinline__ float lrelu(float v) { return v > 0.f ? v : NEG_SLOPE * v; }

__device__ __forceinline__ float f16lo(unsigned u) {
    return __half2float(__ushort_as_half((unsigned short)(u & 0xFFFFu)));
}
__device__ __forceinline__ float f16hi(unsigned u) {
    return __half2float(__ushort_as_half((unsigned short)(u >> 16)));
}
__device__ __forceinline__ unsigned packh2(float a, float b) {
    unsigned lo = __half_as_ushort(__float2half(a));
    unsigned hi = __half_as_ushort(__float2half(b));
    return (hi << 16) | lo;
}
__device__ __forceinline__ float fdot2u(unsigned a, unsigned b, float c) {
    union { unsigned u; half2_t h; } ua, ub;
    ua.u = a; ub.u = b;
    return __builtin_amdgcn_fdot2(ua.h, ub.h, c, false);
}

// ---- prep: pack W1 (f32 [128k][128c]) into f16x2 pairs w1h[kp*128 + col] ----
__global__ __launch_bounds__(256) void k_prepw1(const float* __restrict__ W1,
                                                unsigned* __restrict__ w1h) {
    int i = blockIdx.x * 256 + threadIdx.x;   // 0..8191
    int kp = i >> 7, col = i & 127;
    w1h[i] = packh2(W1[(2 * kp) * 128 + col], W1[(2 * kp + 1) * 128 + col]);
}

// ---- Fused launch 1: edge partition (blocks [0,PART_B)) + layer-1 GEMM ----
// gemm1: x staged as f16 pairs (16 KB, full K), W1 from pre-packed f16x2 table,
// inner loop = v_dot2_f32_f16 (2 MAC/instr, f32 accum). LDS issue and VALU both ~halved.
__global__ __launch_bounds__(256) void k_part_gemm1(
        const int* __restrict__ ei, int* __restrict__ gcur, int* __restrict__ packed,
        const float* __restrict__ x, const unsigned* __restrict__ w1h,
        const float* __restrict__ a_src, const float* __restrict__ a_dst,
        unsigned short* __restrict__ h1h, float* __restrict__ als,
        float* __restrict__ ald) {
    __shared__ __align__(16) union {
        unsigned xs16[64 * 64];                   // 16 KB: [node][kp] f16x2
        struct { int lcnt[NBKT]; int gpos[NBKT]; int lcur[NBKT]; } p;  // part role
    } sm;
    int t = threadIdx.x;
    if (blockIdx.x < PART_B) {
        // ---------------- partition role ----------------
        for (int i = t; i < NBKT; i += 256) sm.p.lcnt[i] = 0;
        __syncthreads();
        size_t base = (size_t)blockIdx.x * EPB;
        for (int i = t; i < EPB; i += 256) {
            size_t e = base + i;
            if (e < E_TOT) {
                int d = (e < N_EDGES) ? ei[N_EDGES + e] : (int)(e - N_EDGES);
                atomicAdd(&sm.p.lcnt[d >> BSH], 1);
            }
        }
        __syncthreads();
        for (int i = t; i < NBKT; i += 256) {
            int c = sm.p.lcnt[i];
            sm.p.gpos[i] = c ? (i * CAP + atomicAdd(&gcur[i], c)) : 0;
            sm.p.lcur[i] = 0;
        }
        __syncthreads();
        for (int i = t; i < EPB; i += 256) {
            size_t e = base + i;
            if (e < E_TOT) {
                int s, d;
                if (e < N_EDGES) { s = ei[e]; d = ei[N_EDGES + e]; }
                else             { s = (int)(e - N_EDGES); d = s; }
                int b = d >> BSH;
                int c = atomicAdd(&sm.p.lcur[b], 1);
                packed[sm.p.gpos[b] + c] = ((d & (BSZ - 1)) << 17) | s;
            }
        }
        return;
    }
    // ---------------- gemm1 role ----------------
    int c = t & 31, rg = t >> 5;
    int nb = (blockIdx.x - PART_B) * 64;
    const float4* xv4 = (const float4*)x;
    uint4* xs4 = (uint4*)sm.xs16;
    // stage: 1024 uint4 slots; slot -> node = slot>>4, kq = slot&15 (4 kp each)
#pragma unroll
    for (int i = 0; i < 4; ++i) {
        int slot = t + i * 256;
        int node = slot >> 4, kq = slot & 15;
        int n = nb + node;
        if (n < N_NODES) {
            float4 a = xv4[(size_t)n * 32 + kq * 2];
            float4 b = xv4[(size_t)n * 32 + kq * 2 + 1];
            uint4 p;
            p.x = packh2(a.x, a.y);
            p.y = packh2(a.z, a.w);
            p.z = packh2(b.x, b.y);
            p.w = packh2(b.z, b.w);
            xs4[slot] = p;
        }
    }
    __syncthreads();
    const uint4* w1h4 = (const uint4*)w1h;
    float4 acc[8];
#pragma unroll
    for (int i = 0; i < 8; ++i) acc[i] = make_float4(0.f, 0.f, 0.f, 0.f);
    for (int kq = 0; kq < 16; ++kq) {
        uint4 wa = w1h4[(kq * 4 + 0) * 32 + c];
        uint4 wb = w1h4[(kq * 4 + 1) * 32 + c];
        uint4 wc2 = w1h4[(kq * 4 + 2) * 32 + c];
        uint4 wd = w1h4[(kq * 4 + 3) * 32 + c];
#pragma unroll
        for (int i = 0; i < 8; ++i) {
            uint4 xq = *(const uint4*)&sm.xs16[(rg + 8 * i) * 64 + kq * 4];
            acc[i].x = fdot2u(xq.x, wa.x, acc[i].x);
            acc[i].y = fdot2u(xq.x, wa.y, acc[i].y);
            acc[i].z = fdot2u(xq.x, wa.z, acc[i].z);
            acc[i].w = fdot2u(xq.x, wa.w, acc[i].w);
            acc[i].x = fdot2u(xq.y, wb.x, acc[i].x);
            acc[i].y = fdot2u(xq.y, wb.y, acc[i].y);
            acc[i].z = fdot2u(xq.y, wb.z, acc[i].z);
            acc[i].w = fdot2u(xq.y, wb.w, acc[i].w);
            acc[i].x = fdot2u(xq.z, wc2.x, acc[i].x);
            acc[i].y = fdot2u(xq.z, wc2.y, acc[i].y);
            acc[i].z = fdot2u(xq.z, wc2.z, acc[i].z);
            acc[i].w = fdot2u(xq.z, wc2.w, acc[i].w);
            acc[i].x = fdot2u(xq.w, wd.x, acc[i].x);
            acc[i].y = fdot2u(xq.w, wd.y, acc[i].y);
            acc[i].z = fdot2u(xq.w, wd.z, acc[i].z);
            acc[i].w = fdot2u(xq.w, wd.w, acc[i].w);
        }
    }
    float4 as4 = ((const float4*)a_src)[c];
    float4 ad4 = ((const float4*)a_dst)[c];
#pragma unroll
    for (int i = 0; i < 8; ++i) {
        int n = nb + rg + 8 * i;
        if (n < N_NODES) {
            ushort4 hb;
            hb.x = __half_as_ushort(__float2half(acc[i].x));
            hb.y = __half_as_ushort(__float2half(acc[i].y));
            hb.z = __half_as_ushort(__float2half(acc[i].z));
            hb.w = __half_as_ushort(__float2half(acc[i].w));
            ((ushort4*)h1h)[(size_t)n * 32 + c] = hb;
        }
        float vs = acc[i].x * as4.x + acc[i].y * as4.y + acc[i].z * as4.z + acc[i].w * as4.w;
        float vd = acc[i].x * ad4.x + acc[i].y * ad4.y + acc[i].z * ad4.z + acc[i].w * ad4.w;
        vs += __shfl_down(vs, 4, 8); vs += __shfl_down(vs, 2, 8); vs += __shfl_down(vs, 1, 8);
        vd += __shfl_down(vd, 4, 8); vd += __shfl_down(vd, 2, 8); vd += __shfl_down(vd, 1, 8);
        if ((c & 7) == 0 && n < N_NODES) {
            int h = c >> 3;
            als[n * 4 + h] = vs;
            ald[n * 4 + h] = vd;
        }
    }
}

// ---- per-bucket: count from cursor, local scan -> rowptr+deg, col scatter ----
__global__ __launch_bounds__(512) void k_build(const int* __restrict__ packed,
                                               const int* __restrict__ gcur,
                                               int* __restrict__ rowptr,
                                               int* __restrict__ deg,
                                               int* __restrict__ col) {
    int t = threadIdx.x;
    int b = blockIdx.x;
    int nb = b << BSH;
    int ebeg = b * CAP;
    int eend = ebeg + gcur[b];     // relative cursor
    __shared__ int cnt[BSZ];
    __shared__ int ps[BSZ];
    cnt[t] = 0;
    __syncthreads();
    for (int i = ebeg + t; i < eend; i += 512)
        atomicAdd(&cnt[packed[i] >> 17], 1);
    __syncthreads();
    int v = cnt[t];
    ps[t] = v;
    __syncthreads();
    for (int off = 1; off < 512; off <<= 1) {
        int u = (t >= off) ? ps[t - off] : 0;
        __syncthreads();
        ps[t] += u;
        __syncthreads();
    }
    int myofs = ebeg + ps[t] - v;   // padded-global col offset of node nb+t
    int n = nb + t;
    if (n < N_NODES) { rowptr[n] = myofs; deg[n] = v; }
    __syncthreads();
    cnt[t] = myofs;                  // reuse as global-position cursor
    __syncthreads();
    for (int i = ebeg + t; i < eend; i += 512) {
        int p = packed[i];
        int pos = atomicAdd(&cnt[p >> 17], 1);
        col[pos] = p & 0x1FFFF;
    }
}

// ---- Layer 1 aggregation: wave/node, 4 edges/iter uint4, fp16 out1 ----
__global__ __launch_bounds__(256) void k_agg1(const unsigned short* __restrict__ h1h,
                                              const float* __restrict__ als,
                                              const float* __restrict__ ald,
                                              const int* __restrict__ rowptr,
                                              const int* __restrict__ deg,
                                              const int* __restrict__ col,
                                              const float* __restrict__ b1,
                                              unsigned short* __restrict__ out1h) {
    __shared__ float sex_all[4][64 * 4];   // per-wave ex[q][head]
    __shared__ int   scol_all[4][64];      // per-wave col cache
    int w = threadIdx.x >> 6;
    int lane = threadIdx.x & 63;
    int n = blockIdx.x * 4 + w;
    int slot = lane >> 4, cg = lane & 15;
    int hd = cg >> 2;
    float* sex = sex_all[w];
    int* scol = scol_all[w];
    float4 ald4 = ((const float4*)ald)[n];
    int beg = rowptr[n], dtot = deg[n];
    float a0 = 0.f, a1 = 0.f, a2 = 0.f, a3 = 0.f;
    float a4 = 0.f, a5 = 0.f, a6 = 0.f, a7 = 0.f, den = 0.f;
    const float4* als4p = (const float4*)als;
    for (int base = 0; base < dtot; base += 64) {
        int cnt = min(64, dtot - base);
        int myc = 0;
        if (lane < cnt) myc = col[beg + base + lane];
        // WAR: previous chunk's ds_reads must drain before overwriting LDS
        __asm__ volatile("s_waitcnt lgkmcnt(0)" ::: "memory");
        if (lane < cnt) {
            scol[lane] = myc;
            float4 as4 = als4p[myc];
            float4 e4;
            e4.x = __expf(lrelu(as4.x + ald4.x));
            e4.y = __expf(lrelu(as4.y + ald4.y));
            e4.z = __expf(lrelu(as4.z + ald4.z));
            e4.w = __expf(lrelu(as4.w + ald4.w));
            ((float4*)sex)[lane] = e4;
        }
        __asm__ volatile("s_waitcnt lgkmcnt(0)" ::: "memory");
#pragma unroll 2
        for (int q4 = 0; q4 < cnt; q4 += 4) {
            int myq = q4 + slot;
            int cq = min(myq, cnt - 1);
            int s = scol[cq];
            float ex = (myq < cnt) ? sex[cq * 4 + hd] : 0.f;
            uint4 hv = *(const uint4*)((const char*)h1h + (((size_t)s << 8) + (cg << 4)));
            a0 = fmaf(ex, f16lo(hv.x), a0);
            a1 = fmaf(ex, f16hi(hv.x), a1);
            a2 = fmaf(ex, f16lo(hv.y), a2);
            a3 = fmaf(ex, f16hi(hv.y), a3);
            a4 = fmaf(ex, f16lo(hv.z), a4);
            a5 = fmaf(ex, f16hi(hv.z), a5);
            a6 = fmaf(ex, f16lo(hv.w), a6);
            a7 = fmaf(ex, f16hi(hv.w), a7);
            den += ex;
        }
    }
    a0 += __shfl_xor(a0, 16, 64); a1 += __shfl_xor(a1, 16, 64);
    a2 += __shfl_xor(a2, 16, 64); a3 += __shfl_xor(a3, 16, 64);
    a4 += __shfl_xor(a4, 16, 64); a5 += __shfl_xor(a5, 16, 64);
    a6 += __shfl_xor(a6, 16, 64); a7 += __shfl_xor(a7, 16, 64);
    den += __shfl_xor(den, 16, 64);
    a0 += __shfl_xor(a0, 32, 64); a1 += __shfl_xor(a1, 32, 64);
    a2 += __shfl_xor(a2, 32, 64); a3 += __shfl_xor(a3, 32, 64);
    a4 += __shfl_xor(a4, 32, 64); a5 += __shfl_xor(a5, 32, 64);
    a6 += __shfl_xor(a6, 32, 64); a7 += __shfl_xor(a7, 32, 64);
    den += __shfl_xor(den, 32, 64);
    if (lane < 16) {
        float inv = 1.0f / den;
        float4 bA = ((const float4*)b1)[2 * lane];
        float4 bB = ((const float4*)b1)[2 * lane + 1];
        float o0 = fmaxf(fmaf(a0, inv, bA.x), 0.f);
        float o1 = fmaxf(fmaf(a1, inv, bA.y), 0.f);
        float o2 = fmaxf(fmaf(a2, inv, bA.z), 0.f);
        float o3 = fmaxf(fmaf(a3, inv, bA.w), 0.f);
        float o4 = fmaxf(fmaf(a4, inv, bB.x), 0.f);
        float o5 = fmaxf(fmaf(a5, inv, bB.y), 0.f);
        float o6 = fmaxf(fmaf(a6, inv, bB.z), 0.f);
        float o7 = fmaxf(fmaf(a7, inv, bB.w), 0.f);
        uint4 pk;
        pk.x = packh2(o0, o1);
        pk.y = packh2(o2, o3);
        pk.z = packh2(o4, o5);
        pk.w = packh2(o6, o7);
        ((uint4*)out1h)[(size_t)n * 16 + lane] = pk;  // ch 8*lane..8*lane+7
    }
}

// ---- Layer 2 GEMM: h2(fp16) = out1h(fp16) @ W2, fused logits ----
__global__ __launch_bounds__(256) void k_gemm2(const unsigned short* __restrict__ out1h,
                                               const float* __restrict__ W2,
                                               const float* __restrict__ a_src,
                                               const float* __restrict__ a_dst,
                                               unsigned short* __restrict__ h2h,
                                               float* __restrict__ als,
                                               float* __restrict__ ald) {
    __shared__ __align__(16) float xs[16 * 132];    // 8448 B
    __shared__ __align__(16) float w2t[16 * 132];   // 8448 B, W2T[c][k]
    int t = threadIdx.x;
    // stage W2 transposed: W2 row-major [128][16]
#pragma unroll
    for (int i = 0; i < 8; ++i) {
        int idx = t + i * 256;            // 0..2047
        int k = idx >> 4, c = idx & 15;
        w2t[c * 132 + k] = W2[idx];
    }
    // stage x tile: 16 nodes x 128 ch fp16 = 4 KB = 256 uint4
    {
        uint4 v = ((const uint4*)out1h)[(size_t)blockIdx.x * 256 + t];
        int node = t >> 4, cb = (t & 15) * 8;
        float* dst = &xs[node * 132 + cb];
        dst[0] = f16lo(v.x); dst[1] = f16hi(v.x);
        dst[2] = f16lo(v.y); dst[3] = f16hi(v.y);
        dst[4] = f16lo(v.z); dst[5] = f16hi(v.z);
        dst[6] = f16lo(v.w); dst[7] = f16hi(v.w);
    }
    __syncthreads();
    int r = t >> 4, c = t & 15;
    const float4* xr4 = (const float4*)&xs[r * 132];
    const float4* wr4 = (const float4*)&w2t[c * 132];
    float acc = 0.f;
#pragma unroll 8
    for (int k4 = 0; k4 < 32; ++k4) {
        float4 xv = xr4[k4];
        float4 wv = wr4[k4];
        acc = fmaf(xv.x, wv.x, acc);
        acc = fmaf(xv.y, wv.y, acc);
        acc = fmaf(xv.z, wv.z, acc);
        acc = fmaf(xv.w, wv.w, acc);
    }
    int n = blockIdx.x * 16 + r;
    h2h[(size_t)n * 16 + c] = __half_as_ushort(__float2half(acc));
    float vs = acc * a_src[c];
    float vd = acc * a_dst[c];
#pragma unroll
    for (int off = 8; off >= 1; off >>= 1) {
        vs += __shfl_down(vs, off, 16);
        vd += __shfl_down(vd, off, 16);
    }
    if (c == 0) { als[n] = vs; ald[n] = vd; }
}

// ---- Layer 2 aggregation: wave/node, 16 edges/iter, batched exp in LDS ----
__global__ __launch_bounds__(256) void k_agg2(const unsigned short* __restrict__ h2h,
                                              const float* __restrict__ als,
                                              const float* __restrict__ ald,
                                              const int* __restrict__ rowptr,
                                              const int* __restrict__ deg,
                                              const int* __restrict__ col,
                                              const float* __restrict__ b2,
                                              float* __restrict__ out) {
    __shared__ float sex_all[4][64];
    __shared__ int   scol_all[4][64];
    int w = threadIdx.x >> 6;
    int lane = threadIdx.x & 63;
    int n = blockIdx.x * 4 + w;
    int slot = lane >> 2, q = lane & 3;
    float* sex = sex_all[w];
    int* scol = scol_all[w];
    float ad = ald[n];
    int beg = rowptr[n], dtot = deg[n];
    float a0 = 0.f, a1 = 0.f, a2 = 0.f, a3 = 0.f, den = 0.f;
    for (int base = 0; base < dtot; base += 64) {
        int cnt = min(64, dtot - base);
        int myc = 0;
        if (lane < cnt) myc = col[beg + base + lane];
        __asm__ volatile("s_waitcnt lgkmcnt(0)" ::: "memory");
        if (lane < cnt) {
            scol[lane] = myc;
            sex[lane] = __expf(lrelu(als[myc] + ad));
        }
        __asm__ volatile("s_waitcnt lgkmcnt(0)" ::: "memory");
#pragma unroll 2
        for (int q16 = 0; q16 < cnt; q16 += 16) {
            int myq = q16 + slot;
            int cq = min(myq, cnt - 1);
            int s = scol[cq];
            float ex = (myq < cnt) ? sex[cq] : 0.f;
            uint2 hv = *(const uint2*)((const char*)h2h + ((size_t)s * 32u + (q << 3)));
            a0 = fmaf(ex, f16lo(hv.x), a0);
            a1 = fmaf(ex, f16hi(hv.x), a1);
            a2 = fmaf(ex, f16lo(hv.y), a2);
            a3 = fmaf(ex, f16hi(hv.y), a3);
            den += ex;
        }
    }
#pragma unroll
    for (int off = 4; off <= 32; off <<= 1) {
        a0 += __shfl_xor(a0, off, 64);
        a1 += __shfl_xor(a1, off, 64);
        a2 += __shfl_xor(a2, off, 64);
        a3 += __shfl_xor(a3, off, 64);
        den += __shfl_xor(den, off, 64);
    }
    if (slot == 0) {
        float inv = 1.0f / den;
        float4 b4 = ((const float4*)b2)[q];
        float4 o;
        o.x = fmaf(a0, inv, b4.x);
        o.y = fmaf(a1, inv, b4.y);
        o.z = fmaf(a2, inv, b4.z);
        o.w = fmaf(a3, inv, b4.w);
        ((float4*)out)[(size_t)n * 4 + q] = o;
    }
}

extern "C" void kernel_launch(void* const* d_in, const int* in_sizes, int n_in,
                              void* d_out, int out_size, void* d_ws, size_t ws_size,
                              hipStream_t stream) {
    const float* x   = (const float*)d_in[0];
    const int*   ei  = (const int*)d_in[1];
    const float* W1  = (const float*)d_in[2];
    const float* as1 = (const float*)d_in[3];
    const float* ad1 = (const float*)d_in[4];
    const float* b1  = (const float*)d_in[5];
    const float* W2  = (const float*)d_in[6];
    const float* as2 = (const float*)d_in[7];
    const float* ad2 = (const float*)d_in[8];
    const float* b2  = (const float*)d_in[9];
    float* out = (float*)d_out;

    char* ws = (char*)d_ws;
    size_t off = 0;
    auto alloc = [&](size_t bytes) -> void* {
        void* p = ws + off;
        off += (bytes + 255) & ~(size_t)255;
        return p;
    };
    unsigned short* h1h  = (unsigned short*)alloc((size_t)N_NODES * 128 * 2);
    unsigned short* o1h  = (unsigned short*)alloc((size_t)N_NODES * 128 * 2);
    float* als1v = (float*)alloc((size_t)N_NODES * 4 * 4);
    float* ald1v = (float*)alloc((size_t)N_NODES * 4 * 4);
    unsigned short* h2h = (unsigned short*)alloc((size_t)N_NODES * 16 * 2);
    float* als2v = (float*)alloc((size_t)N_NODES * 4);
    float* ald2v = (float*)alloc((size_t)N_NODES * 4);
    int* rowptr  = (int*)alloc((size_t)N_NODES * 4);
    int* degv    = (int*)alloc((size_t)N_NODES * 4);
    int* gcur    = (int*)alloc((size_t)NBKT * 4);
    int* packed  = (int*)alloc((size_t)NBKT * CAP * 4);
    int* colA    = (int*)alloc((size_t)NBKT * CAP * 4);
    unsigned* w1h = (unsigned*)alloc((size_t)64 * 128 * 4);   // f16x2-packed W1

    hipMemsetAsync(gcur, 0, (size_t)NBKT * 4, stream);
    k_prepw1<<<32, 256, 0, stream>>>(W1, w1h);
    k_part_gemm1<<<PART_B + GEMM1_B, 256, 0, stream>>>(ei, gcur, packed,
                                                       x, w1h, as1, ad1, h1h, als1v, ald1v);
    k_build<<<NBKT, 512, 0, stream>>>(packed, gcur, rowptr, degv, colA);
    k_agg1<<<N_NODES / 4, 256, 0, stream>>>(h1h, als1v, ald1v, rowptr, degv, colA, b1, o1h);
    k_gemm2<<<N_NODES / 16, 256, 0, stream>>>(o1h, W2, as2, ad2, h2h, als2v, ald2v);
    k_agg2<<<N_NODES / 4, 256, 0, stream>>>(h2h, als2v, ald2v, rowptr, degv, colA, b2, out);
}